// Round 1
// baseline (518.123 us; speedup 1.0000x reference)
//
#include <hip/hip_runtime.h>
#include <hip/hip_bf16.h>

// Problem constants (from reference)
#define BATCH 64
#define CHN 3
#define HH 224
#define WW 224
#define PIX (HH * WW)          // 50176
#define NSEG 196
#define MAXP 400
#define KDIM (CHN * MAXP)      // 1200
#define DN 768

// chunking for stable rank assignment
#define CHSZ 512
#define NCH (PIX / CHSZ)       // 98  (exact: 98*512 = 50176)

// ---------------------------------------------------------------------------
// Pass 1: per-chunk per-segment histogram
// grid: BATCH*NCH blocks x 512 threads
__global__ void k_hist(const int* __restrict__ seg, int* __restrict__ hist) {
    __shared__ int cnt[NSEG];
    int blk = blockIdx.x;
    int b = blk / NCH, ch = blk % NCH;
    int tid = threadIdx.x;
    if (tid < NSEG) cnt[tid] = 0;
    __syncthreads();
    int s = seg[(size_t)b * PIX + ch * CHSZ + tid];
    atomicAdd(&cnt[s], 1);
    __syncthreads();
    if (tid < NSEG) hist[(size_t)blk * NSEG + tid] = cnt[tid];
}

// ---------------------------------------------------------------------------
// Pass 2: exclusive prefix over chunks for each (b, s), in place.
// one thread per (b,s): 12544 threads
__global__ void k_scan(int* __restrict__ hist) {
    int i = blockIdx.x * blockDim.x + threadIdx.x;
    if (i >= BATCH * NSEG) return;
    int b = i / NSEG, s = i % NSEG;
    int run = 0;
    for (int c = 0; c < NCH; ++c) {
        size_t idx = ((size_t)b * NCH + c) * NSEG + s;
        int t = hist[idx];
        hist[idx] = run;
        run += t;
    }
}

// ---------------------------------------------------------------------------
// Pass 3: stable in-chunk rank + scatter into feats [B*S][KDIM]
// grid: BATCH*NCH blocks x 512 threads (8 waves, serialized for order)
__global__ void k_scatter(const float* __restrict__ img,
                          const int* __restrict__ seg,
                          const int* __restrict__ offs,
                          float* __restrict__ feats) {
    __shared__ int cnt[NSEG];
    int blk = blockIdx.x;
    int b = blk / NCH, ch = blk % NCH;
    int tid = threadIdx.x;
    int lane = tid & 63, wid = tid >> 6;
    if (tid < NSEG) cnt[tid] = offs[(size_t)blk * NSEG + tid];
    __syncthreads();

    int p = ch * CHSZ + tid;
    int sv = seg[(size_t)b * PIX + p];

    // emulated match_any across the 64-lane wave (stable: row-major order)
    int first = -1, before = 0, total = 0;
    #pragma unroll 8
    for (int l = 0; l < 64; ++l) {
        int other = __shfl(sv, l);
        if (other == sv) {
            total++;
            if (l < lane) before++;
            if (first < 0) first = l;
        }
    }
    // wave-serialized base fetch (stable order across waves within the chunk)
    int base = 0;
    for (int w = 0; w < 8; ++w) {
        if (wid == w && lane == first) base = atomicAdd(&cnt[sv], total);
        __syncthreads();
    }
    base = __shfl(base, first);
    int r = base + before;

    if (r < MAXP) {
        const float* ib = img + (size_t)b * CHN * PIX + p;
        size_t fb = ((size_t)(b * NSEG + sv)) * KDIM + r;
        feats[fb]            = ib[0];
        feats[fb + MAXP]     = ib[PIX];
        feats[fb + 2 * MAXP] = ib[2 * PIX];
    }
}

// ---------------------------------------------------------------------------
// Pass 4: fp32 GEMM  C[12544,768] = feats[12544,1200] @ W[1200,768] + bias
// BM=128 BN=64 BK=16, 256 threads, 8x4 micro-tile, reg-prefetch
#define BM 128
#define BN 64
#define BK 16
__global__ __launch_bounds__(256) void k_gemm(const float* __restrict__ A,
                                              const float* __restrict__ Bw,
                                              const float* __restrict__ bias,
                                              float* __restrict__ Co) {
    __shared__ float As[BK][BM];
    __shared__ float Bs[BK][BN];
    int bn = blockIdx.x;   // 12  (x-fast: co-scheduled blocks share the A panel)
    int bm = blockIdx.y;   // 98
    int tid = threadIdx.x;

    int ar  = tid >> 2;    // 0..63   A-load row (and row+64)
    int akq = tid & 3;     // 0..3    A-load k-quad
    int bk  = tid >> 4;    // 0..15   B-load k
    int bnq = tid & 15;    // 0..15   B-load n-quad
    int ty  = tid >> 4;    // 0..15   compute row group (8 rows)
    int tx  = tid & 15;    // 0..15   compute col group (4 cols)

    const float* Aptr = A + (size_t)(bm * BM) * KDIM;
    float acc[8][4] = {};

    float4 a0, a1, bb;
    // prefetch kt = 0
    a0 = *(const float4*)(Aptr + (size_t)ar * KDIM + akq * 4);
    a1 = *(const float4*)(Aptr + (size_t)(ar + 64) * KDIM + akq * 4);
    bb = *(const float4*)(Bw + (size_t)bk * DN + bn * BN + bnq * 4);

    const int NT = KDIM / BK;  // 75
    for (int kt = 0; kt < NT; ++kt) {
        __syncthreads();
        As[akq * 4 + 0][ar] = a0.x;
        As[akq * 4 + 1][ar] = a0.y;
        As[akq * 4 + 2][ar] = a0.z;
        As[akq * 4 + 3][ar] = a0.w;
        As[akq * 4 + 0][ar + 64] = a1.x;
        As[akq * 4 + 1][ar + 64] = a1.y;
        As[akq * 4 + 2][ar + 64] = a1.z;
        As[akq * 4 + 3][ar + 64] = a1.w;
        *(float4*)&Bs[bk][bnq * 4] = bb;
        __syncthreads();

        if (kt + 1 < NT) {
            int k0 = (kt + 1) * BK;
            a0 = *(const float4*)(Aptr + (size_t)ar * KDIM + k0 + akq * 4);
            a1 = *(const float4*)(Aptr + (size_t)(ar + 64) * KDIM + k0 + akq * 4);
            bb = *(const float4*)(Bw + (size_t)(k0 + bk) * DN + bn * BN + bnq * 4);
        }

        #pragma unroll
        for (int k = 0; k < BK; ++k) {
            float4 x0 = *(const float4*)&As[k][ty * 8];
            float4 x1 = *(const float4*)&As[k][ty * 8 + 4];
            float4 y  = *(const float4*)&Bs[k][tx * 4];
            float a8[8] = {x0.x, x0.y, x0.z, x0.w, x1.x, x1.y, x1.z, x1.w};
            float b4[4] = {y.x, y.y, y.z, y.w};
            #pragma unroll
            for (int i = 0; i < 8; ++i)
                #pragma unroll
                for (int j = 0; j < 4; ++j)
                    acc[i][j] += a8[i] * b4[j];
        }
    }

    int col = bn * BN + tx * 4;
    float4 bv = *(const float4*)(bias + col);
    #pragma unroll
    for (int i = 0; i < 8; ++i) {
        int row = bm * BM + ty * 8 + i;
        float4 o;
        o.x = acc[i][0] + bv.x;
        o.y = acc[i][1] + bv.y;
        o.z = acc[i][2] + bv.z;
        o.w = acc[i][3] + bv.w;
        *(float4*)(Co + (size_t)row * DN + col) = o;
    }
}

// ---------------------------------------------------------------------------
extern "C" void kernel_launch(void* const* d_in, const int* in_sizes, int n_in,
                              void* d_out, int out_size, void* d_ws, size_t ws_size,
                              hipStream_t stream) {
    const float* img = (const float*)d_in[0];
    const int*   seg = (const int*)d_in[1];
    const float* W   = (const float*)d_in[2];
    const float* bia = (const float*)d_in[3];
    float* out = (float*)d_out;

    const size_t FEATS_BYTES = (size_t)BATCH * NSEG * KDIM * sizeof(float); // 60,211,200
    float* feats = (float*)d_ws;
    int*   hist  = (int*)((char*)d_ws + FEATS_BYTES);

    // zero feats (padding must be zero; ws is poisoned each launch)
    hipMemsetAsync(d_ws, 0, FEATS_BYTES, stream);

    k_hist<<<BATCH * NCH, CHSZ, 0, stream>>>(seg, hist);
    k_scan<<<(BATCH * NSEG + 255) / 256, 256, 0, stream>>>(hist);
    k_scatter<<<BATCH * NCH, CHSZ, 0, stream>>>(img, seg, hist, feats);

    dim3 grid(DN / BN, (BATCH * NSEG) / BM);  // (12, 98)
    k_gemm<<<grid, 256, 0, stream>>>(feats, W, bia, out);
}

// Round 2
// 292.014 us; speedup vs baseline: 1.7743x; 1.7743x over previous
//
#include <hip/hip_runtime.h>
#include <hip/hip_bf16.h>
#include <stdint.h>

// Problem constants
#define BATCH 64
#define CHN 3
#define HH 224
#define WW 224
#define PIX (HH * WW)          // 50176
#define NSEG 196
#define MAXP 400
#define KDIM (CHN * MAXP)      // 1200
#define DN 768

#define KP4 1216               // K padded to mult of 32 (uint32 hi/lo pairs per row)
#define NTK 38                 // 1216 / 32 K-steps
#define MROWS (BATCH * NSEG)   // 12544

// chunking for stable rank assignment
#define CHSZ 512
#define NCH (PIX / CHSZ)       // 98

typedef short short8 __attribute__((ext_vector_type(8)));
typedef float f32x4 __attribute__((ext_vector_type(4)));
typedef unsigned int uint4v __attribute__((ext_vector_type(4)));

// pack fp32 -> (bf16_hi << 16) | bf16_lo  with hi = rn(v), lo = rn(v - hi)
__device__ __forceinline__ uint32_t packhl(float v) {
    uint32_t x = __float_as_uint(v);
    uint32_t hi = (x + 0x7FFFu + ((x >> 16) & 1u)) >> 16;
    float r = v - __uint_as_float(hi << 16);
    uint32_t y = __float_as_uint(r);
    uint32_t lo = (y + 0x7FFFu + ((y >> 16) & 1u)) >> 16;
    return (hi << 16) | lo;
}

// ---------------------------------------------------------------------------
// Pass 1: per-chunk per-segment histogram
__global__ void k_hist(const int* __restrict__ seg, int* __restrict__ hist) {
    __shared__ int cnt[NSEG];
    int blk = blockIdx.x;
    int b = blk / NCH, ch = blk % NCH;
    int tid = threadIdx.x;
    if (tid < NSEG) cnt[tid] = 0;
    __syncthreads();
    int s = seg[(size_t)b * PIX + ch * CHSZ + tid];
    atomicAdd(&cnt[s], 1);
    __syncthreads();
    if (tid < NSEG) hist[(size_t)blk * NSEG + tid] = cnt[tid];
}

// ---------------------------------------------------------------------------
// Pass 2: exclusive prefix over chunks for each (b, s), in place.
__global__ void k_scan(int* __restrict__ hist) {
    int i = blockIdx.x * blockDim.x + threadIdx.x;
    if (i >= BATCH * NSEG) return;
    int b = i / NSEG, s = i % NSEG;
    int run = 0;
    for (int c = 0; c < NCH; ++c) {
        size_t idx = ((size_t)b * NCH + c) * NSEG + s;
        int t = hist[idx];
        hist[idx] = run;
        run += t;
    }
}

// ---------------------------------------------------------------------------
// Pass 3: stable in-chunk rank + scatter packed bf16 hi/lo pairs into
// Apair [MROWS][KP4] (uint32 per element). Layout k = c*MAXP + r.
__global__ void k_scatter(const float* __restrict__ img,
                          const int* __restrict__ seg,
                          const int* __restrict__ offs,
                          uint32_t* __restrict__ Apair) {
    __shared__ int cnt[NSEG];
    int blk = blockIdx.x;
    int b = blk / NCH, ch = blk % NCH;
    int tid = threadIdx.x;
    int lane = tid & 63, wid = tid >> 6;
    if (tid < NSEG) cnt[tid] = offs[(size_t)blk * NSEG + tid];
    __syncthreads();

    int p = ch * CHSZ + tid;
    int sv = seg[(size_t)b * PIX + p];

    // emulated match_any across the 64-lane wave (stable row-major order)
    int first = -1, before = 0, total = 0;
    #pragma unroll 8
    for (int l = 0; l < 64; ++l) {
        int other = __shfl(sv, l);
        if (other == sv) {
            total++;
            if (l < lane) before++;
            if (first < 0) first = l;
        }
    }
    int base = 0;
    for (int w = 0; w < 8; ++w) {
        if (wid == w && lane == first) base = atomicAdd(&cnt[sv], total);
        __syncthreads();
    }
    base = __shfl(base, first);
    int r = base + before;

    if (r < MAXP) {
        const float* ib = img + (size_t)b * CHN * PIX + p;
        uint32_t* row = Apair + (size_t)(b * NSEG + sv) * KP4;
        row[r]            = packhl(ib[0]);
        row[r + MAXP]     = packhl(ib[PIX]);
        row[r + 2 * MAXP] = packhl(ib[2 * PIX]);
    }
}

// ---------------------------------------------------------------------------
// Pass 4: W [1200][768] fp32 -> Wt [768][KP4] packed bf16 hi/lo, transposed.
// grid (38 k-tiles, 24 n-tiles) x 256 threads
__global__ void k_wprep(const float* __restrict__ W, uint32_t* __restrict__ Wt) {
    __shared__ float t[32][33];
    int kt = blockIdx.x, nt = blockIdx.y;
    int tid = threadIdx.x;
    int tx = tid & 31, ty = tid >> 5;  // 32 x 8
    #pragma unroll
    for (int i = 0; i < 4; ++i) {
        int k = kt * 32 + i * 8 + ty;
        int n = nt * 32 + tx;
        t[i * 8 + ty][tx] = (k < KDIM) ? W[(size_t)k * DN + n] : 0.0f;
    }
    __syncthreads();
    #pragma unroll
    for (int i = 0; i < 4; ++i) {
        int n = nt * 32 + i * 8 + ty;
        int k = kt * 32 + tx;
        Wt[(size_t)n * KP4 + k] = packhl(t[tx][i * 8 + ty]);
    }
}

// ---------------------------------------------------------------------------
// Pass 5: bf16x3 MFMA GEMM. C[12544][768] = A * W + bias (fp32-accurate).
// 128x128 tile, BK=32, 4 waves (2x2), double-buffered LDS, XOR-swizzled.
__device__ __forceinline__ void gld16(const void* g, void* l) {
    __builtin_amdgcn_global_load_lds(
        (const __attribute__((address_space(1))) unsigned int*)g,
        (__attribute__((address_space(3))) unsigned int*)l, 16, 0, 0);
}

__global__ __launch_bounds__(256) void k_gemm(const uint32_t* __restrict__ A,
                                              const uint32_t* __restrict__ Bw,
                                              const float* __restrict__ bias,
                                              float* __restrict__ Co) {
    // [buf][A=0/B=1][row*32 + elem]   (row = 128B of packed pairs, swizzled)
    __shared__ uint32_t lds[2][2][128 * 32];
    int bn = blockIdx.x;   // 6
    int bm = blockIdx.y;   // 98
    int tid = threadIdx.x;
    int lane = tid & 63, w = tid >> 6;
    int wm = w >> 1, wn = w & 1;
    int srow = lane >> 3, sslot = lane & 7;   // staging decomposition
    int kb = lane >> 4, r15 = lane & 15;      // fragment decomposition

    const uint32_t* Abase = A + (size_t)(bm * 128) * KP4;
    const uint32_t* Bbase = Bw + (size_t)(bn * 128) * KP4;

    f32x4 acc[4][4] = {};

#define STAGE(buf, kt) do {                                                   \
    _Pragma("unroll")                                                         \
    for (int q = 0; q < 4; ++q) {                                             \
        int rb = (q * 4 + w) * 8;                                             \
        int row = rb + srow;                                                  \
        int sp = sslot ^ (row & 7);                                           \
        gld16(Abase + (size_t)row * KP4 + (kt) * 32 + sp * 4,                 \
              &lds[buf][0][rb * 32]);                                         \
        gld16(Bbase + (size_t)row * KP4 + (kt) * 32 + sp * 4,                 \
              &lds[buf][1][rb * 32]);                                         \
    }                                                                         \
} while (0)

    STAGE(0, 0);
    __syncthreads();

    int cur = 0;
    for (int kt = 0; kt < NTK; ++kt) {
        if (kt + 1 < NTK) STAGE(cur ^ 1, kt + 1);

        short8 ah[4], al[4], bh[4], bl[4];
        #pragma unroll
        for (int mi = 0; mi < 4; ++mi) {
            int row = wm * 64 + mi * 16 + r15;
            int s0 = (2 * kb) ^ (row & 7), s1 = (2 * kb + 1) ^ (row & 7);
            uint4v w0 = *(const uint4v*)&lds[cur][0][row * 32 + s0 * 4];
            uint4v w1 = *(const uint4v*)&lds[cur][0][row * 32 + s1 * 4];
            union { uint32_t u[4]; short8 s; } H, L;
            H.u[0] = __builtin_amdgcn_perm(w0.y, w0.x, 0x07060302u);
            H.u[1] = __builtin_amdgcn_perm(w0.w, w0.z, 0x07060302u);
            H.u[2] = __builtin_amdgcn_perm(w1.y, w1.x, 0x07060302u);
            H.u[3] = __builtin_amdgcn_perm(w1.w, w1.z, 0x07060302u);
            L.u[0] = __builtin_amdgcn_perm(w0.y, w0.x, 0x05040100u);
            L.u[1] = __builtin_amdgcn_perm(w0.w, w0.z, 0x05040100u);
            L.u[2] = __builtin_amdgcn_perm(w1.y, w1.x, 0x05040100u);
            L.u[3] = __builtin_amdgcn_perm(w1.w, w1.z, 0x05040100u);
            ah[mi] = H.s; al[mi] = L.s;
        }
        #pragma unroll
        for (int ni = 0; ni < 4; ++ni) {
            int row = wn * 64 + ni * 16 + r15;
            int s0 = (2 * kb) ^ (row & 7), s1 = (2 * kb + 1) ^ (row & 7);
            uint4v w0 = *(const uint4v*)&lds[cur][1][row * 32 + s0 * 4];
            uint4v w1 = *(const uint4v*)&lds[cur][1][row * 32 + s1 * 4];
            union { uint32_t u[4]; short8 s; } H, L;
            H.u[0] = __builtin_amdgcn_perm(w0.y, w0.x, 0x07060302u);
            H.u[1] = __builtin_amdgcn_perm(w0.w, w0.z, 0x07060302u);
            H.u[2] = __builtin_amdgcn_perm(w1.y, w1.x, 0x07060302u);
            H.u[3] = __builtin_amdgcn_perm(w1.w, w1.z, 0x07060302u);
            L.u[0] = __builtin_amdgcn_perm(w0.y, w0.x, 0x05040100u);
            L.u[1] = __builtin_amdgcn_perm(w0.w, w0.z, 0x05040100u);
            L.u[2] = __builtin_amdgcn_perm(w1.y, w1.x, 0x05040100u);
            L.u[3] = __builtin_amdgcn_perm(w1.w, w1.z, 0x05040100u);
            bh[ni] = H.s; bl[ni] = L.s;
        }

        #pragma unroll
        for (int mi = 0; mi < 4; ++mi)
            #pragma unroll
            for (int ni = 0; ni < 4; ++ni) {
                acc[mi][ni] = __builtin_amdgcn_mfma_f32_16x16x32_bf16(
                    ah[mi], bh[ni], acc[mi][ni], 0, 0, 0);
                acc[mi][ni] = __builtin_amdgcn_mfma_f32_16x16x32_bf16(
                    al[mi], bh[ni], acc[mi][ni], 0, 0, 0);
                acc[mi][ni] = __builtin_amdgcn_mfma_f32_16x16x32_bf16(
                    ah[mi], bl[ni], acc[mi][ni], 0, 0, 0);
            }

        __syncthreads();
        cur ^= 1;
    }
#undef STAGE

    // Epilogue: C row = bm*128 + wm*64 + mi*16 + (lane>>4)*4 + e
    //           C col = bn*128 + wn*64 + ni*16 + (lane&15)
    #pragma unroll
    for (int ni = 0; ni < 4; ++ni) {
        int col = bn * 128 + wn * 64 + ni * 16 + r15;
        float bv = bias[col];
        #pragma unroll
        for (int mi = 0; mi < 4; ++mi) {
            int rbase = bm * 128 + wm * 64 + mi * 16 + kb * 4;
            #pragma unroll
            for (int e = 0; e < 4; ++e)
                Co[(size_t)(rbase + e) * DN + col] = acc[mi][ni][e] + bv;
        }
    }
}

// ---------------------------------------------------------------------------
extern "C" void kernel_launch(void* const* d_in, const int* in_sizes, int n_in,
                              void* d_out, int out_size, void* d_ws, size_t ws_size,
                              hipStream_t stream) {
    const float* img = (const float*)d_in[0];
    const int*   seg = (const int*)d_in[1];
    const float* W   = (const float*)d_in[2];
    const float* bia = (const float*)d_in[3];
    float* out = (float*)d_out;

    const size_t APAIR_BYTES = (size_t)MROWS * KP4 * 4;  // 61,014,016
    uint32_t* Apair = (uint32_t*)d_ws;
    // hist (4.92 MB) and Wt (3.74 MB) share a region: hist's lifetime ends at
    // k_scatter; k_wprep runs after and overwrites it with Wt for k_gemm.
    int*      hist = (int*)((char*)d_ws + APAIR_BYTES);
    uint32_t* Wt   = (uint32_t*)hist;

    hipMemsetAsync(Apair, 0, APAIR_BYTES, stream);

    k_hist<<<BATCH * NCH, CHSZ, 0, stream>>>(seg, hist);
    k_scan<<<(BATCH * NSEG + 255) / 256, 256, 0, stream>>>(hist);
    k_scatter<<<BATCH * NCH, CHSZ, 0, stream>>>(img, seg, hist, Apair);
    k_wprep<<<dim3(NTK, DN / 32), 256, 0, stream>>>(W, Wt);

    dim3 grid(DN / 128, MROWS / 128);  // (6, 98)
    k_gemm<<<grid, 256, 0, stream>>>(Apair, Wt, bia, out);
}

// Round 4
// 236.657 us; speedup vs baseline: 2.1893x; 1.2339x over previous
//
#include <hip/hip_runtime.h>
#include <hip/hip_bf16.h>
#include <stdint.h>

// Problem constants
#define BATCH 64
#define CHN 3
#define HH 224
#define WW 224
#define PIX (HH * WW)          // 50176
#define NSEG 196
#define MAXP 400
#define KDIM (CHN * MAXP)      // 1200
#define DN 768

#define KP4 1216               // K padded to mult of 32 (uint32 hi/lo pairs per row)
#define NTK 38                 // 1216 / 32 K-steps
#define MROWS (BATCH * NSEG)   // 12544

// chunking for stable rank assignment
#define CHSZ 512
#define NCH (PIX / CHSZ)       // 98

typedef short short8 __attribute__((ext_vector_type(8)));
typedef float f32x4 __attribute__((ext_vector_type(4)));
typedef unsigned int uint4v __attribute__((ext_vector_type(4)));

// K permutation: k = c*MAXP + r  ->  kappa = 3r + c (so scatter writes one
// contiguous dwordx3 per pixel). Applied to BOTH A and W; dot product invariant.
// Pad region k in [1200,1216) maps to itself.

// pack fp32 -> (bf16_hi << 16) | bf16_lo  with hi = rn(v), lo = rn(v - hi)
__device__ __forceinline__ uint32_t packhl(float v) {
    uint32_t x = __float_as_uint(v);
    uint32_t hi = (x + 0x7FFFu + ((x >> 16) & 1u)) >> 16;
    float r = v - __uint_as_float(hi << 16);
    uint32_t y = __float_as_uint(r);
    uint32_t lo = (y + 0x7FFFu + ((y >> 16) & 1u)) >> 16;
    return (hi << 16) | lo;
}

// ---------------------------------------------------------------------------
// Pass 1: per-chunk per-segment histogram
__global__ void k_hist(const int* __restrict__ seg, int* __restrict__ hist) {
    __shared__ int cnt[NSEG];
    int blk = blockIdx.x;
    int b = blk / NCH, ch = blk % NCH;
    int tid = threadIdx.x;
    if (tid < NSEG) cnt[tid] = 0;
    __syncthreads();
    int s = seg[(size_t)b * PIX + ch * CHSZ + tid];
    atomicAdd(&cnt[s], 1);
    __syncthreads();
    if (tid < NSEG) hist[(size_t)blk * NSEG + tid] = cnt[tid];
}

// ---------------------------------------------------------------------------
// Pass 2: exclusive prefix over chunks for each (b, s), in place; final total
// goes to counts[b*NSEG+s] (used by k_ztail to zero only the row tails).
__global__ void k_scan(int* __restrict__ hist, int* __restrict__ counts) {
    int i = blockIdx.x * blockDim.x + threadIdx.x;
    if (i >= BATCH * NSEG) return;
    int b = i / NSEG, s = i % NSEG;
    int run = 0;
    for (int c = 0; c < NCH; ++c) {
        size_t idx = ((size_t)b * NCH + c) * NSEG + s;
        int t = hist[idx];
        hist[idx] = run;
        run += t;
    }
    counts[i] = run;
}

// ---------------------------------------------------------------------------
// Pass 2b: zero only the unwritten tail of each A row: [3*min(cnt,400), 1216).
// One wave per row; replaces a full 61 MB memset with ~23 MB targeted zeroing.
__global__ void k_ztail(const int* __restrict__ counts, uint32_t* __restrict__ Apair) {
    int row = blockIdx.x * 4 + (threadIdx.x >> 6);
    int lane = threadIdx.x & 63;
    int cnt = counts[row];
    int start = 3 * min(cnt, MAXP);
    uint32_t* p = Apair + (size_t)row * KP4;
    for (int i = start + lane; i < KP4; i += 64) p[i] = 0u;
}

// ---------------------------------------------------------------------------
// Pass 3: stable rank via ballot-match + cross-wave LDS totals; scatter packed
// bf16 hi/lo pairs as one dwordx3 per pixel at kappa = 3r + c.
__global__ void k_scatter(const float* __restrict__ img,
                          const int* __restrict__ seg,
                          const int* __restrict__ offs,
                          uint32_t* __restrict__ Apair) {
    __shared__ int soff[NSEG];
    __shared__ int wcnt[8][NSEG];
    int blk = blockIdx.x;
    int b = blk / NCH, ch = blk % NCH;
    int tid = threadIdx.x;
    int lane = tid & 63, wid = tid >> 6;

    for (int i = tid; i < 8 * NSEG; i += CHSZ) ((int*)wcnt)[i] = 0;
    if (tid < NSEG) soff[tid] = offs[(size_t)blk * NSEG + tid];
    __syncthreads();

    int p = ch * CHSZ + tid;
    int sv = seg[(size_t)b * PIX + p];

    // ballot-based match_any over the 8 bits of sv (NSEG=196 < 256)
    uint64_t m = ~0ull;
    #pragma unroll
    for (int bit = 0; bit < 8; ++bit) {
        uint64_t bal = __ballot((sv >> bit) & 1);
        m &= ((sv >> bit) & 1) ? bal : ~bal;
    }
    int before = __popcll(m & ((1ull << lane) - 1ull));
    int first  = __builtin_ctzll(m);
    if (lane == first) wcnt[wid][sv] = __popcll(m);
    __syncthreads();

    int base = soff[sv];
    for (int w2 = 0; w2 < wid; ++w2) base += wcnt[w2][sv];  // wid wave-uniform
    int r = base + before;

    if (r < MAXP) {
        const float* ib = img + (size_t)b * CHN * PIX + p;
        uint32_t* dst = Apair + (size_t)(b * NSEG + sv) * KP4 + 3 * r;
        uint32_t v0 = packhl(ib[0]);
        uint32_t v1 = packhl(ib[PIX]);
        uint32_t v2 = packhl(ib[2 * PIX]);
        dst[0] = v0; dst[1] = v1; dst[2] = v2;   // merges to global_store_dwordx3
    }
}

// ---------------------------------------------------------------------------
// Pass 4: W [1200][768] fp32 -> Wt [768][KP4] packed bf16 hi/lo, transposed,
// with the kappa K-permutation.
__global__ void k_wprep(const float* __restrict__ W, uint32_t* __restrict__ Wt) {
    __shared__ float t[32][33];
    int kt = blockIdx.x, nt = blockIdx.y;
    int tid = threadIdx.x;
    int tx = tid & 31, ty = tid >> 5;  // 32 x 8
    #pragma unroll
    for (int i = 0; i < 4; ++i) {
        int k = kt * 32 + i * 8 + ty;
        int n = nt * 32 + tx;
        t[i * 8 + ty][tx] = (k < KDIM) ? W[(size_t)k * DN + n] : 0.0f;
    }
    __syncthreads();
    #pragma unroll
    for (int i = 0; i < 4; ++i) {
        int n = nt * 32 + i * 8 + ty;
        int k = kt * 32 + tx;
        int kap = (k < KDIM) ? 3 * (k % MAXP) + (k / MAXP) : k;
        Wt[(size_t)n * KP4 + kap] = packhl(t[tx][i * 8 + ty]);
    }
}

// ---------------------------------------------------------------------------
// Pass 5: bf16x3 MFMA GEMM. C[12544][768] = A * W + bias (fp32-accurate).
// 128x128 tile, BK=32, 4 waves (2x2), double-buffered LDS, XOR-swizzled,
// XCD-grouped blockIdx so the 6 bn-blocks of one A-panel share one L2.
__device__ __forceinline__ void gld16(const void* g, void* l) {
    __builtin_amdgcn_global_load_lds(
        (const __attribute__((address_space(1))) unsigned int*)g,
        (__attribute__((address_space(3))) unsigned int*)l, 16, 0, 0);
}

#define NWG 588   // 98 bm * 6 bn
__global__ __launch_bounds__(256) void k_gemm(const uint32_t* __restrict__ A,
                                              const uint32_t* __restrict__ Bw,
                                              const float* __restrict__ bias,
                                              float* __restrict__ Co) {
    __shared__ uint32_t lds[2][2][128 * 32];
    // bijective XCD-grouping swizzle (m204): q=73, r=4
    int j = blockIdx.x;
    int xcd = j & 7, sl = j >> 3;
    const int q = NWG / 8, rm = NWG % 8;
    int wgid = (xcd < rm ? xcd * (q + 1) : rm * (q + 1) + (xcd - rm) * q) + sl;
    int bm = wgid / 6, bn = wgid % 6;

    int tid = threadIdx.x;
    int lane = tid & 63, w = tid >> 6;
    int wm = w >> 1, wn = w & 1;
    int srow = lane >> 3, sslot = lane & 7;   // staging decomposition
    int kb = lane >> 4, r15 = lane & 15;      // fragment decomposition

    const uint32_t* Abase = A + (size_t)(bm * 128) * KP4;
    const uint32_t* Bbase = Bw + (size_t)(bn * 128) * KP4;

    f32x4 acc[4][4] = {};

#define STAGE(buf, kt) do {                                                   \
    _Pragma("unroll")                                                         \
    for (int qq = 0; qq < 4; ++qq) {                                          \
        int rb = (qq * 4 + w) * 8;                                            \
        int row = rb + srow;                                                  \
        int sp = sslot ^ (row & 7);                                           \
        gld16(Abase + (size_t)row * KP4 + (kt) * 32 + sp * 4,                 \
              &lds[buf][0][rb * 32]);                                         \
        gld16(Bbase + (size_t)row * KP4 + (kt) * 32 + sp * 4,                 \
              &lds[buf][1][rb * 32]);                                         \
    }                                                                         \
} while (0)

    STAGE(0, 0);
    __syncthreads();

    int cur = 0;
    for (int kt = 0; kt < NTK; ++kt) {
        if (kt + 1 < NTK) STAGE(cur ^ 1, kt + 1);

        short8 ah[4], al[4], bh[4], bl[4];
        #pragma unroll
        for (int mi = 0; mi < 4; ++mi) {
            int row = wm * 64 + mi * 16 + r15;
            int s0 = (2 * kb) ^ (row & 7), s1 = (2 * kb + 1) ^ (row & 7);
            uint4v w0 = *(const uint4v*)&lds[cur][0][row * 32 + s0 * 4];
            uint4v w1 = *(const uint4v*)&lds[cur][0][row * 32 + s1 * 4];
            union { uint32_t u[4]; short8 s; } H, L;
            H.u[0] = __builtin_amdgcn_perm(w0.y, w0.x, 0x07060302u);
            H.u[1] = __builtin_amdgcn_perm(w0.w, w0.z, 0x07060302u);
            H.u[2] = __builtin_amdgcn_perm(w1.y, w1.x, 0x07060302u);
            H.u[3] = __builtin_amdgcn_perm(w1.w, w1.z, 0x07060302u);
            L.u[0] = __builtin_amdgcn_perm(w0.y, w0.x, 0x05040100u);
            L.u[1] = __builtin_amdgcn_perm(w0.w, w0.z, 0x05040100u);
            L.u[2] = __builtin_amdgcn_perm(w1.y, w1.x, 0x05040100u);
            L.u[3] = __builtin_amdgcn_perm(w1.w, w1.z, 0x05040100u);
            ah[mi] = H.s; al[mi] = L.s;
        }
        #pragma unroll
        for (int ni = 0; ni < 4; ++ni) {
            int row = wn * 64 + ni * 16 + r15;
            int s0 = (2 * kb) ^ (row & 7), s1 = (2 * kb + 1) ^ (row & 7);
            uint4v w0 = *(const uint4v*)&lds[cur][1][row * 32 + s0 * 4];
            uint4v w1 = *(const uint4v*)&lds[cur][1][row * 32 + s1 * 4];
            union { uint32_t u[4]; short8 s; } H, L;
            H.u[0] = __builtin_amdgcn_perm(w0.y, w0.x, 0x07060302u);
            H.u[1] = __builtin_amdgcn_perm(w0.w, w0.z, 0x07060302u);
            H.u[2] = __builtin_amdgcn_perm(w1.y, w1.x, 0x07060302u);
            H.u[3] = __builtin_amdgcn_perm(w1.w, w1.z, 0x07060302u);
            L.u[0] = __builtin_amdgcn_perm(w0.y, w0.x, 0x05040100u);
            L.u[1] = __builtin_amdgcn_perm(w0.w, w0.z, 0x05040100u);
            L.u[2] = __builtin_amdgcn_perm(w1.y, w1.x, 0x05040100u);
            L.u[3] = __builtin_amdgcn_perm(w1.w, w1.z, 0x05040100u);
            bh[ni] = H.s; bl[ni] = L.s;
        }

        #pragma unroll
        for (int mi = 0; mi < 4; ++mi)
            #pragma unroll
            for (int ni = 0; ni < 4; ++ni) {
                acc[mi][ni] = __builtin_amdgcn_mfma_f32_16x16x32_bf16(
                    ah[mi], bh[ni], acc[mi][ni], 0, 0, 0);
                acc[mi][ni] = __builtin_amdgcn_mfma_f32_16x16x32_bf16(
                    al[mi], bh[ni], acc[mi][ni], 0, 0, 0);
                acc[mi][ni] = __builtin_amdgcn_mfma_f32_16x16x32_bf16(
                    ah[mi], bl[ni], acc[mi][ni], 0, 0, 0);
            }

        __syncthreads();
        cur ^= 1;
    }
#undef STAGE

    #pragma unroll
    for (int ni = 0; ni < 4; ++ni) {
        int col = bn * 128 + wn * 64 + ni * 16 + r15;
        float bv = bias[col];
        #pragma unroll
        for (int mi = 0; mi < 4; ++mi) {
            int rbase = bm * 128 + wm * 64 + mi * 16 + kb * 4;
            #pragma unroll
            for (int e = 0; e < 4; ++e)
                Co[(size_t)(rbase + e) * DN + col] = acc[mi][ni][e] + bv;
        }
    }
}

// ---------------------------------------------------------------------------
extern "C" void kernel_launch(void* const* d_in, const int* in_sizes, int n_in,
                              void* d_out, int out_size, void* d_ws, size_t ws_size,
                              hipStream_t stream) {
    const float* img = (const float*)d_in[0];
    const int*   seg = (const int*)d_in[1];
    const float* W   = (const float*)d_in[2];
    const float* bia = (const float*)d_in[3];
    float* out = (float*)d_out;

    const size_t APAIR_BYTES = (size_t)MROWS * KP4 * 4;            // 61,014,016
    const size_t HIST_BYTES  = (size_t)BATCH * NCH * NSEG * 4;     //  4,917,248
    uint32_t* Apair  = (uint32_t*)d_ws;
    int*      hist   = (int*)((char*)d_ws + APAIR_BYTES);
    int*      counts = (int*)((char*)d_ws + APAIR_BYTES + HIST_BYTES);
    // Wt overlaps hist: hist is dead after k_scatter; k_wprep runs after it.
    uint32_t* Wt     = (uint32_t*)hist;

    k_hist<<<BATCH * NCH, CHSZ, 0, stream>>>(seg, hist);
    k_scan<<<(BATCH * NSEG + 255) / 256, 256, 0, stream>>>(hist, counts);
    k_ztail<<<MROWS / 4, 256, 0, stream>>>(counts, Apair);
    k_scatter<<<BATCH * NCH, CHSZ, 0, stream>>>(img, seg, hist, Apair);
    k_wprep<<<dim3(NTK, DN / 32), 256, 0, stream>>>(W, Wt);

    k_gemm<<<NWG, 256, 0, stream>>>(Apair, Wt, bia, out);
}